// Round 2
// 362.617 us; speedup vs baseline: 1.0015x; 1.0015x over previous
//
#include <hip/hip_runtime.h>
#include <math.h>

#define NE 8
#define HD 2048
#define ID 1408
#define NT 512
#define FP8MAX 448.0f

typedef __attribute__((ext_vector_type(4))) float floatx4;

__device__ __forceinline__ floatx4 fzero4() {
    floatx4 z; z.x = 0.f; z.y = 0.f; z.z = 0.f; z.w = 0.f; return z;
}

// ---- ws layout (bytes) ----
#define OFF_OFFS  0                         // int[16]
#define OFF_TOK   1024                      // int[1024]
#define OFF_WGT   8192                      // float[1024]
#define OFF_ENT   16384                     // int[1024]  (slot -> entry)
#define OFF_XSG   32768                     // float[1024*16] entry-ordered x scales
#define OFF_XG    131072                    // u8[1024*2048] entry-ordered x codes (2 MB)
#define OFF_HS    (3*1024*1024)             // float[1024*11]
#define OFF_HQ    (3*1024*1024 + 65536)     // u8[1024*1408]
#define OFF_GU0   (5*1024*1024)             // float[1024*2816] K-half-0 partials (11.5 MB)
#define OFF_GU1   (17*1024*1024)            // float[1024*2816] K-half-1 partials

#define LDA 136   // LDS row pitch for 128-byte fp8 rows

// ---------------- routing ----------------
__global__ void route_kernel(const int* __restrict__ tki,
                             const float* __restrict__ tkw,
                             int* __restrict__ offs,
                             int* __restrict__ tok,
                             float* __restrict__ wgt,
                             int* __restrict__ ent) {
    __shared__ int cnt[NE];
    __shared__ int cur[NE];
    __shared__ int base[NE + 1];
    int tid = threadIdx.x;               // 1024 threads, one per (token, slot)
    if (tid < NE) { cnt[tid] = 0; cur[tid] = 0; }
    __syncthreads();
    int e = tki[tid];
    atomicAdd(&cnt[e], 1);
    __syncthreads();
    if (tid == 0) {
        int s = 0;
        for (int i = 0; i < NE; i++) { base[i] = s; s += cnt[i]; }
        base[NE] = s;
    }
    __syncthreads();
    int pos = atomicAdd(&cur[e], 1);
    int j = base[e] + pos;
    tok[j] = tid >> 1;                   // token id
    wgt[j] = tkw[tid];
    ent[tid] = j;                        // inverse map: (token,slot) -> entry
    if (tid <= NE) offs[tid] = base[tid];
}

// ---------------- x quantization + entry-ordered scatter ---------------------
__global__ void quant_x_kernel(const float* __restrict__ x,
                               const int* __restrict__ ent,
                               unsigned char* __restrict__ xg,
                               float* __restrict__ xsg) {
    int wid = (blockIdx.x * 256 + threadIdx.x) >> 6;   // 0..8191
    int lane = threadIdx.x & 63;
    int t = wid >> 4;
    int b = wid & 15;
    const float2 v = *(const float2*)(x + (long)t * HD + b * 128 + lane * 2);
    float am = fmaxf(fabsf(v.x), fabsf(v.y));
    #pragma unroll
    for (int m = 32; m; m >>= 1) am = fmaxf(am, __shfl_xor(am, m));
    float scale = fmaxf(am, 1e-12f) / FP8MAX;
    int p = __builtin_amdgcn_cvt_pk_fp8_f32(v.x / scale, v.y / scale, 0, false);
    unsigned short pk = (unsigned short)(p & 0xffff);
    int e0 = ent[2 * t], e1 = ent[2 * t + 1];
    *(unsigned short*)(xg + (long)e0 * HD + b * 128 + lane * 2) = pk;
    *(unsigned short*)(xg + (long)e1 * HD + b * 128 + lane * 2) = pk;
    if (lane == 0) { xsg[e0 * 16 + b] = scale; xsg[e1 * 16 + b] = scale; }
}

// ---------------- h: sum K-halves, silu*up, quantize -------------------------
__global__ void quant_h_kernel(const float* __restrict__ gu0,
                               const float* __restrict__ gu1,
                               unsigned char* __restrict__ hq,
                               float* __restrict__ hs) {
    int wid = (blockIdx.x * 256 + threadIdx.x) >> 6;   // 0..11263
    int lane = threadIdx.x & 63;
    int j = wid / 11;
    int b = wid - j * 11;
    long base = (long)j * 2816 + b * 128 + lane * 2;
    float2 ga = *(const float2*)(gu0 + base);
    float2 gb = *(const float2*)(gu1 + base);
    float2 ua = *(const float2*)(gu0 + base + 1408);
    float2 ub = *(const float2*)(gu1 + base + 1408);
    float gx = ga.x + gb.x, gy = ga.y + gb.y;
    float ux = ua.x + ub.x, uy = ua.y + ub.y;
    float hx = (gx / (1.0f + expf(-gx))) * ux;
    float hy = (gy / (1.0f + expf(-gy))) * uy;
    float am = fmaxf(fabsf(hx), fabsf(hy));
    #pragma unroll
    for (int m = 32; m; m >>= 1) am = fmaxf(am, __shfl_xor(am, m));
    float scale = fmaxf(am, 1e-12f) / FP8MAX;
    int p = __builtin_amdgcn_cvt_pk_fp8_f32(hx / scale, hy / scale, 0, false);
    *(unsigned short*)(hq + (long)j * ID + b * 128 + lane * 2) =
        (unsigned short)(p & 0xffff);
    if (lane == 0) hs[j * 11 + b] = scale;
}

// ---------------- gemm1: BM=128 x 32 gate/up col pairs, K-split-2 ------------
// r6 structure + T14 async-STAGE pipeline: prefetch next-kb A/B tiles into
// registers right after the first barrier so HBM latency overlaps the MFMA
// phase instead of stalling the staging phase.
__global__ __launch_bounds__(256, 3) void gemm1_kernel(
    const unsigned char* __restrict__ xg,
    const float* __restrict__ xsg,
    const float* __restrict__ wgu,   // [E][2816][2048] fp32 codes
    const float* __restrict__ sgu,   // [E][22][16]
    const int* __restrict__ offs,
    float* __restrict__ gu0,
    float* __restrict__ gu1) {
    int e = blockIdx.z;
    int mt = blockIdx.y;
    int jb = blockIdx.x >> 1;        // 0..43 (32 gate/up col pairs each)
    int kh = blockIdx.x & 1;         // K half
    int o0 = offs[e], o1 = offs[e + 1];
    int ne = o1 - o0;
    int m0 = mt * 128;
    if (m0 >= ne) return;
    int rem = ne - m0;
    int j0 = o0 + m0;

    __shared__ __align__(16) unsigned char Asm[128 * LDA];  // 17408
    __shared__ __align__(16) unsigned char Bsm[64 * LDA];   // 8704
    __shared__ __align__(16) float sxa[128 * 20];           // 10240

    int tid = threadIdx.x;
    {   // stage per-row x scales (2 threads/row)
        int r = tid >> 1, q = tid & 1;
        int j = j0 + r; if (j >= o1) j = o0;
        float4 s0 = *(const float4*)(xsg + j * 16 + q * 8);
        float4 s1 = *(const float4*)(xsg + j * 16 + q * 8 + 4);
        *(float4*)&sxa[r * 20 + q * 8] = s0;
        *(float4*)&sxa[r * 20 + q * 8 + 4] = s1;
    }

    int wave = tid >> 6;
    int lane = tid & 63;
    int lr = lane & 15;
    int lq = lane >> 4;

    // A staging: 4 steps x (8 threads/row, 16B each) — fully coalesced
    int aseg = tid & 7;
    int arow0 = tid >> 3;            // 0..31
    const unsigned char* aBase0;
    const unsigned char* aBase1;
    const unsigned char* aBase2;
    const unsigned char* aBase3;
    {
        int j;
        j = j0 + arow0;       if (j >= o1) j = o0; aBase0 = xg + (long)j * HD + aseg * 16;
        j = j0 + 32 + arow0;  if (j >= o1) j = o0; aBase1 = xg + (long)j * HD + aseg * 16;
        j = j0 + 64 + arow0;  if (j >= o1) j = o0; aBase2 = xg + (long)j * HD + aseg * 16;
        j = j0 + 96 + arow0;  if (j >= o1) j = o0; aBase3 = xg + (long)j * HD + aseg * 16;
    }

    // B staging: coalesced — 32 consecutive lanes cover one row's 512B chunk.
    int bcol = tid & 31;             // float4 (16B) index within 128-float chunk
    int brow0 = tid >> 5;            // 0..7
    const float* bG = wgu + ((long)e * 2816 + jb * 32 + brow0) * HD + bcol * 4;
    const float* bU = wgu + ((long)e * 2816 + 1408 + jb * 32 + brow0) * HD + bcol * 4;
    const float* sgp = sgu + (e * 22 + (jb >> 2)) * 16;
    const float* sup = sgu + (e * 22 + 11 + (jb >> 2)) * 16;

    floatx4 facc[8];
    #pragma unroll
    for (int i = 0; i < 8; i++) facc[i] = fzero4();

    int kbS = kh * 8, kbE = kbS + 8;

    // ---- prologue: prefetch first kb into registers ----
    uint4 a0 = *(const uint4*)(aBase0 + kbS * 128);
    uint4 a1 = *(const uint4*)(aBase1 + kbS * 128);
    uint4 a2 = *(const uint4*)(aBase2 + kbS * 128);
    uint4 a3 = *(const uint4*)(aBase3 + kbS * 128);
    float4 f0 = *(const float4*)(bG + kbS * 128);
    float4 f1 = *(const float4*)(bG + kbS * 128 + 8 * HD);
    float4 f2 = *(const float4*)(bG + kbS * 128 + 16 * HD);
    float4 f3 = *(const float4*)(bG + kbS * 128 + 24 * HD);
    float4 f4 = *(const float4*)(bU + kbS * 128);
    float4 f5 = *(const float4*)(bU + kbS * 128 + 8 * HD);
    float4 f6 = *(const float4*)(bU + kbS * 128 + 16 * HD);
    float4 f7 = *(const float4*)(bU + kbS * 128 + 24 * HD);

    for (int kb = kbS; kb < kbE; kb++) {
        // ---- staging phase: regs already hold this kb's tiles ----
        {
            *(uint4*)(&Asm[(arow0)      * LDA + aseg * 16]) = a0;
            *(uint4*)(&Asm[(arow0 + 32) * LDA + aseg * 16]) = a1;
            *(uint4*)(&Asm[(arow0 + 64) * LDA + aseg * 16]) = a2;
            *(uint4*)(&Asm[(arow0 + 96) * LDA + aseg * 16]) = a3;
            int p0 = __builtin_amdgcn_cvt_pk_fp8_f32(f0.x, f0.y, 0, false);
            p0 = __builtin_amdgcn_cvt_pk_fp8_f32(f0.z, f0.w, p0, true);
            int p1 = __builtin_amdgcn_cvt_pk_fp8_f32(f1.x, f1.y, 0, false);
            p1 = __builtin_amdgcn_cvt_pk_fp8_f32(f1.z, f1.w, p1, true);
            int p2 = __builtin_amdgcn_cvt_pk_fp8_f32(f2.x, f2.y, 0, false);
            p2 = __builtin_amdgcn_cvt_pk_fp8_f32(f2.z, f2.w, p2, true);
            int p3 = __builtin_amdgcn_cvt_pk_fp8_f32(f3.x, f3.y, 0, false);
            p3 = __builtin_amdgcn_cvt_pk_fp8_f32(f3.z, f3.w, p3, true);
            int p4 = __builtin_amdgcn_cvt_pk_fp8_f32(f4.x, f4.y, 0, false);
            p4 = __builtin_amdgcn_cvt_pk_fp8_f32(f4.z, f4.w, p4, true);
            int p5 = __builtin_amdgcn_cvt_pk_fp8_f32(f5.x, f5.y, 0, false);
            p5 = __builtin_amdgcn_cvt_pk_fp8_f32(f5.z, f5.w, p5, true);
            int p6 = __builtin_amdgcn_cvt_pk_fp8_f32(f6.x, f6.y, 0, false);
            p6 = __builtin_amdgcn_cvt_pk_fp8_f32(f6.z, f6.w, p6, true);
            int p7 = __builtin_amdgcn_cvt_pk_fp8_f32(f7.x, f7.y, 0, false);
            p7 = __builtin_amdgcn_cvt_pk_fp8_f32(f7.z, f7.w, p7, true);
            *(unsigned int*)(&Bsm[(brow0)      * LDA + bcol * 4]) = (unsigned int)p0;
            *(unsigned int*)(&Bsm[(brow0 + 8)  * LDA + bcol * 4]) = (unsigned int)p1;
            *(unsigned int*)(&Bsm[(brow0 + 16) * LDA + bcol * 4]) = (unsigned int)p2;
            *(unsigned int*)(&Bsm[(brow0 + 24) * LDA + bcol * 4]) = (unsigned int)p3;
            *(unsigned int*)(&Bsm[(brow0 + 32) * LDA + bcol * 4]) = (unsigned int)p4;
            *(unsigned int*)(&Bsm[(brow0 + 40) * LDA + bcol * 4]) = (unsigned int)p5;
            *(unsigned int*)(&Bsm[(brow0 + 48) * LDA + bcol * 4]) = (unsigned int)p6;
            *(unsigned int*)(&Bsm[(brow0 + 56) * LDA + bcol * 4]) = (unsigned int)p7;
        }
        __syncthreads();
        // ---- prefetch next kb (clamped; overlaps MFMA phase + barrier) ----
        {
            int kn = (kb + 1 < kbE) ? (kb + 1) : kb;
            a0 = *(const uint4*)(aBase0 + kn * 128);
            a1 = *(const uint4*)(aBase1 + kn * 128);
            a2 = *(const uint4*)(aBase2 + kn * 128);
            a3 = *(const uint4*)(aBase3 + kn * 128);
            f0 = *(const float4*)(bG + kn * 128);
            f1 = *(const float4*)(bG + kn * 128 + 8 * HD);
            f2 = *(const float4*)(bG + kn * 128 + 16 * HD);
            f3 = *(const float4*)(bG + kn * 128 + 24 * HD);
            f4 = *(const float4*)(bU + kn * 128);
            f5 = *(const float4*)(bU + kn * 128 + 8 * HD);
            f6 = *(const float4*)(bU + kn * 128 + 16 * HD);
            f7 = *(const float4*)(bU + kn * 128 + 24 * HD);
        }
        // ---- MFMA phase ----
        floatx4 cacc[8];
        #pragma unroll
        for (int i = 0; i < 8; i++) cacc[i] = fzero4();
        #pragma unroll
        for (int ks = 0; ks < 4; ks++) {
            long a[2], b[4];
            #pragma unroll
            for (int mi = 0; mi < 2; mi++)
                a[mi] = *(const long*)(&Asm[(wave * 32 + mi * 16 + lr) * LDA + ks * 32 + lq * 8]);
            #pragma unroll
            for (int ni = 0; ni < 4; ni++)
                b[ni] = *(const long*)(&Bsm[(ni * 16 + lr) * LDA + ks * 32 + lq * 8]);
            #pragma unroll
            for (int mi = 0; mi < 2; mi++)
                #pragma unroll
                for (int ni = 0; ni < 4; ni++)
                    cacc[mi * 4 + ni] = __builtin_amdgcn_mfma_f32_16x16x32_fp8_fp8(
                        a[mi], b[ni], cacc[mi * 4 + ni], 0, 0, 0);
        }
        float sg = sgp[kb];
        float su = sup[kb];
        #pragma unroll
        for (int mi = 0; mi < 2; mi++) {
            #pragma unroll
            for (int reg = 0; reg < 4; reg++) {
                float sx = sxa[(wave * 32 + mi * 16 + lq * 4 + reg) * 20 + kb];
                #pragma unroll
                for (int ni = 0; ni < 4; ni++) {
                    float sw = (ni < 2) ? sg : su;
                    facc[mi * 4 + ni][reg] += cacc[mi * 4 + ni][reg] * (sw * sx);
                }
            }
        }
        __syncthreads();
    }

    // epilogue: store gate/up fp32 partials (silu happens in quant_h)
    float* gu = kh ? gu1 : gu0;
    #pragma unroll
    for (int mi = 0; mi < 2; mi++) {
        #pragma unroll
        for (int ni = 0; ni < 4; ni++) {
            #pragma unroll
            for (int reg = 0; reg < 4; reg++) {
                int r = wave * 32 + mi * 16 + lq * 4 + reg;
                if (r < rem) {
                    long base = (long)(j0 + r) * 2816;
                    long col = (ni < 2) ? (jb * 32 + ni * 16 + lr)
                                        : (1408 + jb * 32 + (ni - 2) * 16 + lr);
                    gu[base + col] = facc[mi * 4 + ni][reg];
                }
            }
        }
    }
}

// ---------------- gemm2: BM=128 x BN=32 H-cols, K-split-2, atomic scatter ----
// B (HBM weight stream) is register-prefetched one kb ahead; A (hq, 1.4 MB,
// L2-resident) stays load-use to keep VGPRs under the (256,4) cap.
__global__ __launch_bounds__(256, 4) void gemm2_kernel(
    const unsigned char* __restrict__ hq,
    const float* __restrict__ hs,
    const float* __restrict__ wd,    // [E][2048][1408] fp32 codes
    const float* __restrict__ sd,    // [E][16][11]
    const int* __restrict__ offs,
    const int* __restrict__ tok,
    const float* __restrict__ wgt,
    float* __restrict__ out) {
    int e = blockIdx.z;
    int mt = blockIdx.y;
    int jb = blockIdx.x >> 1;        // 0..63 (32 H-cols each)
    int kh = blockIdx.x & 1;
    int o0 = offs[e], o1 = offs[e + 1];
    int ne = o1 - o0;
    int m0 = mt * 128;
    if (m0 >= ne) return;
    int rem = ne - m0;
    int j0 = o0 + m0;

    __shared__ __align__(16) unsigned char Asm[128 * LDA];  // 17408
    __shared__ __align__(16) unsigned char Bsm[32 * LDA];   // 4352
    __shared__ __align__(16) float sha[128 * 12];           // 6144
    __shared__ int tokL[128];
    __shared__ float wgtL[128];

    int tid = threadIdx.x;
    if (tid < 128) {
        int j = j0 + tid;
        int valid = j < o1;
        if (!valid) j = o0;
        tokL[tid] = tok[j];
        wgtL[tid] = valid ? wgt[j] : 0.0f;
        const float* s = hs + j * 11;
        #pragma unroll
        for (int k = 0; k < 11; k++) sha[tid * 12 + k] = s[k];
    }

    int wave = tid >> 6;
    int lane = tid & 63;
    int lr = lane & 15;
    int lq = lane >> 4;

    int aseg = tid & 7;
    int arow0 = tid >> 3;            // 0..31
    const unsigned char* aBase0;
    const unsigned char* aBase1;
    const unsigned char* aBase2;
    const unsigned char* aBase3;
    {
        int j;
        j = j0 + arow0;       if (j >= o1) j = o0; aBase0 = hq + (long)j * ID + aseg * 16;
        j = j0 + 32 + arow0;  if (j >= o1) j = o0; aBase1 = hq + (long)j * ID + aseg * 16;
        j = j0 + 64 + arow0;  if (j >= o1) j = o0; aBase2 = hq + (long)j * ID + aseg * 16;
        j = j0 + 96 + arow0;  if (j >= o1) j = o0; aBase3 = hq + (long)j * ID + aseg * 16;
    }

    // B staging: coalesced — 32 lanes cover one row's 512B chunk
    int bcol = tid & 31;
    int brow0 = tid >> 5;            // 0..7
    const float* bB = wd + ((long)e * HD + jb * 32 + brow0) * ID + bcol * 4;
    const float* sdp = sd + (e * 16 + (jb >> 2)) * 11;

    floatx4 facc[4];
    #pragma unroll
    for (int i = 0; i < 4; i++) facc[i] = fzero4();

    int kb0 = kh ? 6 : 0, kb1 = kh ? 11 : 6;

    // ---- prologue: prefetch first kb's B tile into registers ----
    float4 f0 = *(const float4*)(bB + kb0 * 128);
    float4 f1 = *(const float4*)(bB + kb0 * 128 + 8 * ID);
    float4 f2 = *(const float4*)(bB + kb0 * 128 + 16 * ID);
    float4 f3 = *(const float4*)(bB + kb0 * 128 + 24 * ID);

    for (int kb = kb0; kb < kb1; kb++) {
        {
            uint4 a0 = *(const uint4*)(aBase0 + kb * 128);
            uint4 a1 = *(const uint4*)(aBase1 + kb * 128);
            uint4 a2 = *(const uint4*)(aBase2 + kb * 128);
            uint4 a3 = *(const uint4*)(aBase3 + kb * 128);
            *(uint4*)(&Asm[(arow0)      * LDA + aseg * 16]) = a0;
            *(uint4*)(&Asm[(arow0 + 32) * LDA + aseg * 16]) = a1;
            *(uint4*)(&Asm[(arow0 + 64) * LDA + aseg * 16]) = a2;
            *(uint4*)(&Asm[(arow0 + 96) * LDA + aseg * 16]) = a3;
            int p0 = __builtin_amdgcn_cvt_pk_fp8_f32(f0.x, f0.y, 0, false);
            p0 = __builtin_amdgcn_cvt_pk_fp8_f32(f0.z, f0.w, p0, true);
            int p1 = __builtin_amdgcn_cvt_pk_fp8_f32(f1.x, f1.y, 0, false);
            p1 = __builtin_amdgcn_cvt_pk_fp8_f32(f1.z, f1.w, p1, true);
            int p2 = __builtin_amdgcn_cvt_pk_fp8_f32(f2.x, f2.y, 0, false);
            p2 = __builtin_amdgcn_cvt_pk_fp8_f32(f2.z, f2.w, p2, true);
            int p3 = __builtin_amdgcn_cvt_pk_fp8_f32(f3.x, f3.y, 0, false);
            p3 = __builtin_amdgcn_cvt_pk_fp8_f32(f3.z, f3.w, p3, true);
            *(unsigned int*)(&Bsm[(brow0)      * LDA + bcol * 4]) = (unsigned int)p0;
            *(unsigned int*)(&Bsm[(brow0 + 8)  * LDA + bcol * 4]) = (unsigned int)p1;
            *(unsigned int*)(&Bsm[(brow0 + 16) * LDA + bcol * 4]) = (unsigned int)p2;
            *(unsigned int*)(&Bsm[(brow0 + 24) * LDA + bcol * 4]) = (unsigned int)p3;
        }
        __syncthreads();
        // ---- prefetch next kb's B tile (clamped; overlaps MFMA) ----
        {
            int kn = (kb + 1 < kb1) ? (kb + 1) : kb;
            f0 = *(const float4*)(bB + kn * 128);
            f1 = *(const float4*)(bB + kn * 128 + 8 * ID);
            f2 = *(const float4*)(bB + kn * 128 + 16 * ID);
            f3 = *(const float4*)(bB + kn * 128 + 24 * ID);
        }
        floatx4 cacc[4];
        #pragma unroll
        for (int i = 0; i < 4; i++) cacc[i] = fzero4();
        #pragma unroll
        for (int ks = 0; ks < 4; ks++) {
            long a[2], b[2];
            #pragma unroll
            for (int mi = 0; mi < 2; mi++)
                a[mi] = *(const long*)(&Asm[(wave * 32 + mi * 16 + lr) * LDA + ks * 32 + lq * 8]);
            #pragma unroll
            for (int ni = 0; ni < 2; ni++)
                b[ni] = *(const long*)(&Bsm[(ni * 16 + lr) * LDA + ks * 32 + lq * 8]);
            #pragma unroll
            for (int mi = 0; mi < 2; mi++)
                #pragma unroll
                for (int ni = 0; ni < 2; ni++)
                    cacc[mi * 2 + ni] = __builtin_amdgcn_mfma_f32_16x16x32_fp8_fp8(
                        a[mi], b[ni], cacc[mi * 2 + ni], 0, 0, 0);
        }
        float sw = sdp[kb];
        #pragma unroll
        for (int mi = 0; mi < 2; mi++) {
            #pragma unroll
            for (int reg = 0; reg < 4; reg++) {
                float sh = sha[(wave * 32 + mi * 16 + lq * 4 + reg) * 12 + kb];
                #pragma unroll
                for (int ni = 0; ni < 2; ni++)
                    facc[mi * 2 + ni][reg] += cacc[mi * 2 + ni][reg] * (sw * sh);
            }
        }
        __syncthreads();
    }

    #pragma unroll
    for (int mi = 0; mi < 2; mi++) {
        #pragma unroll
        for (int ni = 0; ni < 2; ni++) {
            #pragma unroll
            for (int reg = 0; reg < 4; reg++) {
                int r = wave * 32 + mi * 16 + lq * 4 + reg;
                if (r < rem) {
                    float v = facc[mi * 2 + ni][reg] * wgtL[r];
                    atomicAdd(out + (long)tokL[r] * HD + jb * 32 + ni * 16 + lr, v);
                }
            }
        }
    }
}

extern "C" void kernel_launch(void* const* d_in, const int* in_sizes, int n_in,
                              void* d_out, int out_size, void* d_ws, size_t ws_size,
                              hipStream_t stream) {
    (void)in_sizes; (void)n_in; (void)out_size; (void)ws_size;
    const float* x   = (const float*)d_in[0];
    const int*   tki = (const int*)d_in[1];
    const float* tkw = (const float*)d_in[2];
    const float* wgu = (const float*)d_in[3];
    const float* sgu = (const float*)d_in[4];
    const float* wd  = (const float*)d_in[5];
    const float* sd  = (const float*)d_in[6];
    float* out = (float*)d_out;
    char* ws = (char*)d_ws;

    int*   offs = (int*)(ws + OFF_OFFS);
    int*   tok  = (int*)(ws + OFF_TOK);
    float* wgt  = (float*)(ws + OFF_WGT);
    int*   ent  = (int*)(ws + OFF_ENT);
    float* xsg  = (float*)(ws + OFF_XSG);
    unsigned char* xg = (unsigned char*)(ws + OFF_XG);
    float* hs   = (float*)(ws + OFF_HS);
    unsigned char* hq = (unsigned char*)(ws + OFF_HQ);
    float* gu0  = (float*)(ws + OFF_GU0);
    float* gu1  = (float*)(ws + OFF_GU1);

    hipMemsetAsync(d_out, 0, (size_t)NT * HD * sizeof(float), stream);
    route_kernel<<<1, 1024, 0, stream>>>(tki, tkw, offs, tok, wgt, ent);
    quant_x_kernel<<<2048, 256, 0, stream>>>(x, ent, xg, xsg);
    gemm1_kernel<<<dim3(88, 8, NE), 256, 0, stream>>>(xg, xsg, wgu, sgu, offs, gu0, gu1);
    quant_h_kernel<<<2816, 256, 0, stream>>>(gu0, gu1, hq, hs);
    gemm2_kernel<<<dim3(128, 8, NE), 256, 0, stream>>>(hq, hs, wd, sd, offs, tok, wgt, out);
}

// Round 3
// 362.324 us; speedup vs baseline: 1.0023x; 1.0008x over previous
//
#include <hip/hip_runtime.h>
#include <math.h>

#define NE 8
#define HD 2048
#define ID 1408
#define NT 512
#define FP8MAX 448.0f

typedef __attribute__((ext_vector_type(4))) float floatx4;

__device__ __forceinline__ floatx4 fzero4() {
    floatx4 z; z.x = 0.f; z.y = 0.f; z.z = 0.f; z.w = 0.f; return z;
}

// ---- ws layout (bytes) ----
#define OFF_OFFS  0                         // int[16]
#define OFF_TOK   1024                      // int[1024]
#define OFF_WGT   8192                      // float[1024]
#define OFF_ENT   16384                     // int[1024]  (slot -> entry)
#define OFF_XSG   32768                     // float[1024*16] entry-ordered x scales
#define OFF_XG    131072                    // u8[1024*2048] entry-ordered x codes (2 MB)
#define OFF_HS    (3*1024*1024)             // float[1024*11]
#define OFF_HQ    (3*1024*1024 + 65536)     // u8[1024*1408]
#define OFF_GU0   (5*1024*1024)             // float[1024*2816] K-half-0 partials (11.5 MB)
#define OFF_GU1   (17*1024*1024)            // float[1024*2816] K-half-1 partials
// gemm2 D-partials reuse GU regions (gu consumed by quant_h before gemm2 runs):
// d0 = OFF_GU0 (1024*2048 fp32 = 8 MB), d1 = OFF_GU1

#define LDA 136   // LDS row pitch for 128-byte fp8 rows

// ---------------- routing ----------------
__global__ void route_kernel(const int* __restrict__ tki,
                             const float* __restrict__ tkw,
                             int* __restrict__ offs,
                             int* __restrict__ tok,
                             float* __restrict__ wgt,
                             int* __restrict__ ent) {
    __shared__ int cnt[NE];
    __shared__ int cur[NE];
    __shared__ int base[NE + 1];
    int tid = threadIdx.x;               // 1024 threads, one per (token, slot)
    if (tid < NE) { cnt[tid] = 0; cur[tid] = 0; }
    __syncthreads();
    int e = tki[tid];
    atomicAdd(&cnt[e], 1);
    __syncthreads();
    if (tid == 0) {
        int s = 0;
        for (int i = 0; i < NE; i++) { base[i] = s; s += cnt[i]; }
        base[NE] = s;
    }
    __syncthreads();
    int pos = atomicAdd(&cur[e], 1);
    int j = base[e] + pos;
    tok[j] = tid >> 1;                   // token id
    wgt[j] = tkw[tid];
    ent[tid] = j;                        // inverse map: (token,slot) -> entry
    if (tid <= NE) offs[tid] = base[tid];
}

// ---------------- x quantization + entry-ordered scatter ---------------------
__global__ void quant_x_kernel(const float* __restrict__ x,
                               const int* __restrict__ ent,
                               unsigned char* __restrict__ xg,
                               float* __restrict__ xsg) {
    int wid = (blockIdx.x * 256 + threadIdx.x) >> 6;   // 0..8191
    int lane = threadIdx.x & 63;
    int t = wid >> 4;
    int b = wid & 15;
    const float2 v = *(const float2*)(x + (long)t * HD + b * 128 + lane * 2);
    float am = fmaxf(fabsf(v.x), fabsf(v.y));
    #pragma unroll
    for (int m = 32; m; m >>= 1) am = fmaxf(am, __shfl_xor(am, m));
    float scale = fmaxf(am, 1e-12f) / FP8MAX;
    int p = __builtin_amdgcn_cvt_pk_fp8_f32(v.x / scale, v.y / scale, 0, false);
    unsigned short pk = (unsigned short)(p & 0xffff);
    int e0 = ent[2 * t], e1 = ent[2 * t + 1];
    *(unsigned short*)(xg + (long)e0 * HD + b * 128 + lane * 2) = pk;
    *(unsigned short*)(xg + (long)e1 * HD + b * 128 + lane * 2) = pk;
    if (lane == 0) { xsg[e0 * 16 + b] = scale; xsg[e1 * 16 + b] = scale; }
}

// ---------------- h: sum K-halves, silu*up, quantize -------------------------
__global__ void quant_h_kernel(const float* __restrict__ gu0,
                               const float* __restrict__ gu1,
                               unsigned char* __restrict__ hq,
                               float* __restrict__ hs) {
    int wid = (blockIdx.x * 256 + threadIdx.x) >> 6;   // 0..11263
    int lane = threadIdx.x & 63;
    int j = wid / 11;
    int b = wid - j * 11;
    long base = (long)j * 2816 + b * 128 + lane * 2;
    float2 ga = *(const float2*)(gu0 + base);
    float2 gb = *(const float2*)(gu1 + base);
    float2 ua = *(const float2*)(gu0 + base + 1408);
    float2 ub = *(const float2*)(gu1 + base + 1408);
    float gx = ga.x + gb.x, gy = ga.y + gb.y;
    float ux = ua.x + ub.x, uy = ua.y + ub.y;
    float hx = (gx / (1.0f + expf(-gx))) * ux;
    float hy = (gy / (1.0f + expf(-gy))) * uy;
    float am = fmaxf(fabsf(hx), fabsf(hy));
    #pragma unroll
    for (int m = 32; m; m >>= 1) am = fmaxf(am, __shfl_xor(am, m));
    float scale = fmaxf(am, 1e-12f) / FP8MAX;
    int p = __builtin_amdgcn_cvt_pk_fp8_f32(hx / scale, hy / scale, 0, false);
    *(unsigned short*)(hq + (long)j * ID + b * 128 + lane * 2) =
        (unsigned short)(p & 0xffff);
    if (lane == 0) hs[j * 11 + b] = scale;
}

// ---------------- gemm1: BM=128 x 32 gate/up col pairs, K-split-2 ------------
__global__ __launch_bounds__(256, 3) void gemm1_kernel(
    const unsigned char* __restrict__ xg,
    const float* __restrict__ xsg,
    const float* __restrict__ wgu,   // [E][2816][2048] fp32 codes
    const float* __restrict__ sgu,   // [E][22][16]
    const int* __restrict__ offs,
    float* __restrict__ gu0,
    float* __restrict__ gu1) {
    int e = blockIdx.z;
    int mt = blockIdx.y;
    int jb = blockIdx.x >> 1;        // 0..43 (32 gate/up col pairs each)
    int kh = blockIdx.x & 1;         // K half
    int o0 = offs[e], o1 = offs[e + 1];
    int ne = o1 - o0;
    int m0 = mt * 128;
    if (m0 >= ne) return;
    int rem = ne - m0;
    int j0 = o0 + m0;

    __shared__ __align__(16) unsigned char Asm[128 * LDA];  // 17408
    __shared__ __align__(16) unsigned char Bsm[64 * LDA];   // 8704
    __shared__ __align__(16) float sxa[128 * 20];           // 10240

    int tid = threadIdx.x;
    {   // stage per-row x scales (2 threads/row)
        int r = tid >> 1, q = tid & 1;
        int j = j0 + r; if (j >= o1) j = o0;
        float4 s0 = *(const float4*)(xsg + j * 16 + q * 8);
        float4 s1 = *(const float4*)(xsg + j * 16 + q * 8 + 4);
        *(float4*)&sxa[r * 20 + q * 8] = s0;
        *(float4*)&sxa[r * 20 + q * 8 + 4] = s1;
    }

    int wave = tid >> 6;
    int lane = tid & 63;
    int lr = lane & 15;
    int lq = lane >> 4;

    // A staging: 4 steps x (8 threads/row, 16B each) — fully coalesced
    int aseg = tid & 7;
    int arow0 = tid >> 3;            // 0..31
    const unsigned char* aBase0;
    const unsigned char* aBase1;
    const unsigned char* aBase2;
    const unsigned char* aBase3;
    {
        int j;
        j = j0 + arow0;       if (j >= o1) j = o0; aBase0 = xg + (long)j * HD + aseg * 16;
        j = j0 + 32 + arow0;  if (j >= o1) j = o0; aBase1 = xg + (long)j * HD + aseg * 16;
        j = j0 + 64 + arow0;  if (j >= o1) j = o0; aBase2 = xg + (long)j * HD + aseg * 16;
        j = j0 + 96 + arow0;  if (j >= o1) j = o0; aBase3 = xg + (long)j * HD + aseg * 16;
    }

    // B staging: coalesced — 32 consecutive lanes cover one row's 512B chunk.
    int bcol = tid & 31;             // float4 (16B) index within 128-float chunk
    int brow0 = tid >> 5;            // 0..7
    const float* bG = wgu + ((long)e * 2816 + jb * 32 + brow0) * HD + bcol * 4;
    const float* bU = wgu + ((long)e * 2816 + 1408 + jb * 32 + brow0) * HD + bcol * 4;
    const float* sgp = sgu + (e * 22 + (jb >> 2)) * 16;
    const float* sup = sgu + (e * 22 + 11 + (jb >> 2)) * 16;

    floatx4 facc[8];
    #pragma unroll
    for (int i = 0; i < 8; i++) facc[i] = fzero4();

    int kbS = kh * 8, kbE = kbS + 8;

    // ---- prologue: prefetch first kb into registers ----
    uint4 a0 = *(const uint4*)(aBase0 + kbS * 128);
    uint4 a1 = *(const uint4*)(aBase1 + kbS * 128);
    uint4 a2 = *(const uint4*)(aBase2 + kbS * 128);
    uint4 a3 = *(const uint4*)(aBase3 + kbS * 128);
    float4 f0 = *(const float4*)(bG + kbS * 128);
    float4 f1 = *(const float4*)(bG + kbS * 128 + 8 * HD);
    float4 f2 = *(const float4*)(bG + kbS * 128 + 16 * HD);
    float4 f3 = *(const float4*)(bG + kbS * 128 + 24 * HD);
    float4 f4 = *(const float4*)(bU + kbS * 128);
    float4 f5 = *(const float4*)(bU + kbS * 128 + 8 * HD);
    float4 f6 = *(const float4*)(bU + kbS * 128 + 16 * HD);
    float4 f7 = *(const float4*)(bU + kbS * 128 + 24 * HD);

    for (int kb = kbS; kb < kbE; kb++) {
        // ---- staging phase: regs already hold this kb's tiles ----
        {
            *(uint4*)(&Asm[(arow0)      * LDA + aseg * 16]) = a0;
            *(uint4*)(&Asm[(arow0 + 32) * LDA + aseg * 16]) = a1;
            *(uint4*)(&Asm[(arow0 + 64) * LDA + aseg * 16]) = a2;
            *(uint4*)(&Asm[(arow0 + 96) * LDA + aseg * 16]) = a3;
            int p0 = __builtin_amdgcn_cvt_pk_fp8_f32(f0.x, f0.y, 0, false);
            p0 = __builtin_amdgcn_cvt_pk_fp8_f32(f0.z, f0.w, p0, true);
            int p1 = __builtin_amdgcn_cvt_pk_fp8_f32(f1.x, f1.y, 0, false);
            p1 = __builtin_amdgcn_cvt_pk_fp8_f32(f1.z, f1.w, p1, true);
            int p2 = __builtin_amdgcn_cvt_pk_fp8_f32(f2.x, f2.y, 0, false);
            p2 = __builtin_amdgcn_cvt_pk_fp8_f32(f2.z, f2.w, p2, true);
            int p3 = __builtin_amdgcn_cvt_pk_fp8_f32(f3.x, f3.y, 0, false);
            p3 = __builtin_amdgcn_cvt_pk_fp8_f32(f3.z, f3.w, p3, true);
            int p4 = __builtin_amdgcn_cvt_pk_fp8_f32(f4.x, f4.y, 0, false);
            p4 = __builtin_amdgcn_cvt_pk_fp8_f32(f4.z, f4.w, p4, true);
            int p5 = __builtin_amdgcn_cvt_pk_fp8_f32(f5.x, f5.y, 0, false);
            p5 = __builtin_amdgcn_cvt_pk_fp8_f32(f5.z, f5.w, p5, true);
            int p6 = __builtin_amdgcn_cvt_pk_fp8_f32(f6.x, f6.y, 0, false);
            p6 = __builtin_amdgcn_cvt_pk_fp8_f32(f6.z, f6.w, p6, true);
            int p7 = __builtin_amdgcn_cvt_pk_fp8_f32(f7.x, f7.y, 0, false);
            p7 = __builtin_amdgcn_cvt_pk_fp8_f32(f7.z, f7.w, p7, true);
            *(unsigned int*)(&Bsm[(brow0)      * LDA + bcol * 4]) = (unsigned int)p0;
            *(unsigned int*)(&Bsm[(brow0 + 8)  * LDA + bcol * 4]) = (unsigned int)p1;
            *(unsigned int*)(&Bsm[(brow0 + 16) * LDA + bcol * 4]) = (unsigned int)p2;
            *(unsigned int*)(&Bsm[(brow0 + 24) * LDA + bcol * 4]) = (unsigned int)p3;
            *(unsigned int*)(&Bsm[(brow0 + 32) * LDA + bcol * 4]) = (unsigned int)p4;
            *(unsigned int*)(&Bsm[(brow0 + 40) * LDA + bcol * 4]) = (unsigned int)p5;
            *(unsigned int*)(&Bsm[(brow0 + 48) * LDA + bcol * 4]) = (unsigned int)p6;
            *(unsigned int*)(&Bsm[(brow0 + 56) * LDA + bcol * 4]) = (unsigned int)p7;
        }
        __syncthreads();
        // ---- prefetch next kb (clamped; overlaps MFMA phase + barrier) ----
        {
            int kn = (kb + 1 < kbE) ? (kb + 1) : kb;
            a0 = *(const uint4*)(aBase0 + kn * 128);
            a1 = *(const uint4*)(aBase1 + kn * 128);
            a2 = *(const uint4*)(aBase2 + kn * 128);
            a3 = *(const uint4*)(aBase3 + kn * 128);
            f0 = *(const float4*)(bG + kn * 128);
            f1 = *(const float4*)(bG + kn * 128 + 8 * HD);
            f2 = *(const float4*)(bG + kn * 128 + 16 * HD);
            f3 = *(const float4*)(bG + kn * 128 + 24 * HD);
            f4 = *(const float4*)(bU + kn * 128);
            f5 = *(const float4*)(bU + kn * 128 + 8 * HD);
            f6 = *(const float4*)(bU + kn * 128 + 16 * HD);
            f7 = *(const float4*)(bU + kn * 128 + 24 * HD);
        }
        // ---- MFMA phase ----
        floatx4 cacc[8];
        #pragma unroll
        for (int i = 0; i < 8; i++) cacc[i] = fzero4();
        #pragma unroll
        for (int ks = 0; ks < 4; ks++) {
            long a[2], b[4];
            #pragma unroll
            for (int mi = 0; mi < 2; mi++)
                a[mi] = *(const long*)(&Asm[(wave * 32 + mi * 16 + lr) * LDA + ks * 32 + lq * 8]);
            #pragma unroll
            for (int ni = 0; ni < 4; ni++)
                b[ni] = *(const long*)(&Bsm[(ni * 16 + lr) * LDA + ks * 32 + lq * 8]);
            #pragma unroll
            for (int mi = 0; mi < 2; mi++)
                #pragma unroll
                for (int ni = 0; ni < 4; ni++)
                    cacc[mi * 4 + ni] = __builtin_amdgcn_mfma_f32_16x16x32_fp8_fp8(
                        a[mi], b[ni], cacc[mi * 4 + ni], 0, 0, 0);
        }
        float sg = sgp[kb];
        float su = sup[kb];
        #pragma unroll
        for (int mi = 0; mi < 2; mi++) {
            #pragma unroll
            for (int reg = 0; reg < 4; reg++) {
                float sx = sxa[(wave * 32 + mi * 16 + lq * 4 + reg) * 20 + kb];
                #pragma unroll
                for (int ni = 0; ni < 4; ni++) {
                    float sw = (ni < 2) ? sg : su;
                    facc[mi * 4 + ni][reg] += cacc[mi * 4 + ni][reg] * (sw * sx);
                }
            }
        }
        __syncthreads();
    }

    // epilogue: store gate/up fp32 partials (silu happens in quant_h)
    float* gu = kh ? gu1 : gu0;
    #pragma unroll
    for (int mi = 0; mi < 2; mi++) {
        #pragma unroll
        for (int ni = 0; ni < 4; ni++) {
            #pragma unroll
            for (int reg = 0; reg < 4; reg++) {
                int r = wave * 32 + mi * 16 + lq * 4 + reg;
                if (r < rem) {
                    long base = (long)(j0 + r) * 2816;
                    long col = (ni < 2) ? (jb * 32 + ni * 16 + lr)
                                        : (1408 + jb * 32 + (ni - 2) * 16 + lr);
                    gu[base + col] = facc[mi * 4 + ni][reg];
                }
            }
        }
    }
}

// ---------------- gemm2: BM=128 x BN=32 H-cols, K-split-2 --------------------
// De-atomic'd: each kh half writes deterministic per-entry partials d0/d1
// (plain coalesced stores) instead of 4.7M same-line atomicAdds into out.
// combine_kernel applies routing weights and sums slots + halves.
__global__ __launch_bounds__(256, 4) void gemm2_kernel(
    const unsigned char* __restrict__ hq,
    const float* __restrict__ hs,
    const float* __restrict__ wd,    // [E][2048][1408] fp32 codes
    const float* __restrict__ sd,    // [E][16][11]
    const int* __restrict__ offs,
    float* __restrict__ d0,
    float* __restrict__ d1) {
    int e = blockIdx.z;
    int mt = blockIdx.y;
    int jb = blockIdx.x >> 1;        // 0..63 (32 H-cols each)
    int kh = blockIdx.x & 1;
    int o0 = offs[e], o1 = offs[e + 1];
    int ne = o1 - o0;
    int m0 = mt * 128;
    if (m0 >= ne) return;
    int rem = ne - m0;
    int j0 = o0 + m0;

    __shared__ __align__(16) unsigned char Asm[128 * LDA];  // 17408
    __shared__ __align__(16) unsigned char Bsm[32 * LDA];   // 4352
    __shared__ __align__(16) float sha[128 * 12];           // 6144

    int tid = threadIdx.x;
    if (tid < 128) {
        int j = j0 + tid;
        if (j >= o1) j = o0;
        const float* s = hs + j * 11;
        #pragma unroll
        for (int k = 0; k < 11; k++) sha[tid * 12 + k] = s[k];
    }

    int wave = tid >> 6;
    int lane = tid & 63;
    int lr = lane & 15;
    int lq = lane >> 4;

    int aseg = tid & 7;
    int arow0 = tid >> 3;            // 0..31
    const unsigned char* aBase0;
    const unsigned char* aBase1;
    const unsigned char* aBase2;
    const unsigned char* aBase3;
    {
        int j;
        j = j0 + arow0;       if (j >= o1) j = o0; aBase0 = hq + (long)j * ID + aseg * 16;
        j = j0 + 32 + arow0;  if (j >= o1) j = o0; aBase1 = hq + (long)j * ID + aseg * 16;
        j = j0 + 64 + arow0;  if (j >= o1) j = o0; aBase2 = hq + (long)j * ID + aseg * 16;
        j = j0 + 96 + arow0;  if (j >= o1) j = o0; aBase3 = hq + (long)j * ID + aseg * 16;
    }

    // B staging: coalesced — 32 lanes cover one row's 512B chunk
    int bcol = tid & 31;
    int brow0 = tid >> 5;            // 0..7
    const float* bB = wd + ((long)e * HD + jb * 32 + brow0) * ID + bcol * 4;
    const float* sdp = sd + (e * 16 + (jb >> 2)) * 11;

    floatx4 facc[4];
    #pragma unroll
    for (int i = 0; i < 4; i++) facc[i] = fzero4();

    int kb0 = kh ? 6 : 0, kb1 = kh ? 11 : 6;

    // ---- prologue: prefetch first kb's B tile into registers ----
    float4 f0 = *(const float4*)(bB + kb0 * 128);
    float4 f1 = *(const float4*)(bB + kb0 * 128 + 8 * ID);
    float4 f2 = *(const float4*)(bB + kb0 * 128 + 16 * ID);
    float4 f3 = *(const float4*)(bB + kb0 * 128 + 24 * ID);

    for (int kb = kb0; kb < kb1; kb++) {
        {
            uint4 a0 = *(const uint4*)(aBase0 + kb * 128);
            uint4 a1 = *(const uint4*)(aBase1 + kb * 128);
            uint4 a2 = *(const uint4*)(aBase2 + kb * 128);
            uint4 a3 = *(const uint4*)(aBase3 + kb * 128);
            *(uint4*)(&Asm[(arow0)      * LDA + aseg * 16]) = a0;
            *(uint4*)(&Asm[(arow0 + 32) * LDA + aseg * 16]) = a1;
            *(uint4*)(&Asm[(arow0 + 64) * LDA + aseg * 16]) = a2;
            *(uint4*)(&Asm[(arow0 + 96) * LDA + aseg * 16]) = a3;
            int p0 = __builtin_amdgcn_cvt_pk_fp8_f32(f0.x, f0.y, 0, false);
            p0 = __builtin_amdgcn_cvt_pk_fp8_f32(f0.z, f0.w, p0, true);
            int p1 = __builtin_amdgcn_cvt_pk_fp8_f32(f1.x, f1.y, 0, false);
            p1 = __builtin_amdgcn_cvt_pk_fp8_f32(f1.z, f1.w, p1, true);
            int p2 = __builtin_amdgcn_cvt_pk_fp8_f32(f2.x, f2.y, 0, false);
            p2 = __builtin_amdgcn_cvt_pk_fp8_f32(f2.z, f2.w, p2, true);
            int p3 = __builtin_amdgcn_cvt_pk_fp8_f32(f3.x, f3.y, 0, false);
            p3 = __builtin_amdgcn_cvt_pk_fp8_f32(f3.z, f3.w, p3, true);
            *(unsigned int*)(&Bsm[(brow0)      * LDA + bcol * 4]) = (unsigned int)p0;
            *(unsigned int*)(&Bsm[(brow0 + 8)  * LDA + bcol * 4]) = (unsigned int)p1;
            *(unsigned int*)(&Bsm[(brow0 + 16) * LDA + bcol * 4]) = (unsigned int)p2;
            *(unsigned int*)(&Bsm[(brow0 + 24) * LDA + bcol * 4]) = (unsigned int)p3;
        }
        __syncthreads();
        // ---- prefetch next kb's B tile (clamped; overlaps MFMA) ----
        {
            int kn = (kb + 1 < kb1) ? (kb + 1) : kb;
            f0 = *(const float4*)(bB + kn * 128);
            f1 = *(const float4*)(bB + kn * 128 + 8 * ID);
            f2 = *(const float4*)(bB + kn * 128 + 16 * ID);
            f3 = *(const float4*)(bB + kn * 128 + 24 * ID);
        }
        floatx4 cacc[4];
        #pragma unroll
        for (int i = 0; i < 4; i++) cacc[i] = fzero4();
        #pragma unroll
        for (int ks = 0; ks < 4; ks++) {
            long a[2], b[2];
            #pragma unroll
            for (int mi = 0; mi < 2; mi++)
                a[mi] = *(const long*)(&Asm[(wave * 32 + mi * 16 + lr) * LDA + ks * 32 + lq * 8]);
            #pragma unroll
            for (int ni = 0; ni < 2; ni++)
                b[ni] = *(const long*)(&Bsm[(ni * 16 + lr) * LDA + ks * 32 + lq * 8]);
            #pragma unroll
            for (int mi = 0; mi < 2; mi++)
                #pragma unroll
                for (int ni = 0; ni < 2; ni++)
                    cacc[mi * 2 + ni] = __builtin_amdgcn_mfma_f32_16x16x32_fp8_fp8(
                        a[mi], b[ni], cacc[mi * 2 + ni], 0, 0, 0);
        }
        float sw = sdp[kb];
        #pragma unroll
        for (int mi = 0; mi < 2; mi++) {
            #pragma unroll
            for (int reg = 0; reg < 4; reg++) {
                float sh = sha[(wave * 32 + mi * 16 + lq * 4 + reg) * 12 + kb];
                #pragma unroll
                for (int ni = 0; ni < 2; ni++)
                    facc[mi * 2 + ni][reg] += cacc[mi * 2 + ni][reg] * (sw * sh);
            }
        }
        __syncthreads();
    }

    float* dp = kh ? d1 : d0;
    #pragma unroll
    for (int mi = 0; mi < 2; mi++) {
        #pragma unroll
        for (int ni = 0; ni < 2; ni++) {
            #pragma unroll
            for (int reg = 0; reg < 4; reg++) {
                int r = wave * 32 + mi * 16 + lq * 4 + reg;
                if (r < rem) {
                    dp[(long)(j0 + r) * HD + jb * 32 + ni * 16 + lr] =
                        facc[mi * 2 + ni][reg];
                }
            }
        }
    }
}

// ---------------- combine: out[t] = sum_slot w * (d0[ent] + d1[ent]) ---------
__global__ void combine_kernel(const float* __restrict__ d0,
                               const float* __restrict__ d1,
                               const int* __restrict__ ent,
                               const float* __restrict__ tkw,
                               float* __restrict__ out) {
    int gid = blockIdx.x * 256 + threadIdx.x;   // 512 tokens * 512 float4 cols
    int t = gid >> 9;
    int c4 = gid & 511;
    int j0 = ent[2 * t], j1 = ent[2 * t + 1];
    float w0 = tkw[2 * t], w1 = tkw[2 * t + 1];
    long b0 = (long)j0 * HD + c4 * 4;
    long b1 = (long)j1 * HD + c4 * 4;
    float4 a0 = *(const float4*)(d0 + b0);
    float4 a1 = *(const float4*)(d1 + b0);
    float4 a2 = *(const float4*)(d0 + b1);
    float4 a3 = *(const float4*)(d1 + b1);
    float4 r;
    r.x = w0 * (a0.x + a1.x) + w1 * (a2.x + a3.x);
    r.y = w0 * (a0.y + a1.y) + w1 * (a2.y + a3.y);
    r.z = w0 * (a0.z + a1.z) + w1 * (a2.z + a3.z);
    r.w = w0 * (a0.w + a1.w) + w1 * (a2.w + a3.w);
    *(float4*)(out + (long)t * HD + c4 * 4) = r;
}

extern "C" void kernel_launch(void* const* d_in, const int* in_sizes, int n_in,
                              void* d_out, int out_size, void* d_ws, size_t ws_size,
                              hipStream_t stream) {
    (void)in_sizes; (void)n_in; (void)out_size; (void)ws_size;
    const float* x   = (const float*)d_in[0];
    const int*   tki = (const int*)d_in[1];
    const float* tkw = (const float*)d_in[2];
    const float* wgu = (const float*)d_in[3];
    const float* sgu = (const float*)d_in[4];
    const float* wd  = (const float*)d_in[5];
    const float* sd  = (const float*)d_in[6];
    float* out = (float*)d_out;
    char* ws = (char*)d_ws;

    int*   offs = (int*)(ws + OFF_OFFS);
    int*   tok  = (int*)(ws + OFF_TOK);
    float* wgt  = (float*)(ws + OFF_WGT);
    int*   ent  = (int*)(ws + OFF_ENT);
    float* xsg  = (float*)(ws + OFF_XSG);
    unsigned char* xg = (unsigned char*)(ws + OFF_XG);
    float* hs   = (float*)(ws + OFF_HS);
    unsigned char* hq = (unsigned char*)(ws + OFF_HQ);
    float* gu0  = (float*)(ws + OFF_GU0);
    float* gu1  = (float*)(ws + OFF_GU1);
    // D-partials alias the gu regions (gu dead after quant_h)
    float* dp0  = (float*)(ws + OFF_GU0);
    float* dp1  = (float*)(ws + OFF_GU1);

    route_kernel<<<1, 1024, 0, stream>>>(tki, tkw, offs, tok, wgt, ent);
    quant_x_kernel<<<2048, 256, 0, stream>>>(x, ent, xg, xsg);
    gemm1_kernel<<<dim3(88, 8, NE), 256, 0, stream>>>(xg, xsg, wgu, sgu, offs, gu0, gu1);
    quant_h_kernel<<<2816, 256, 0, stream>>>(gu0, gu1, hq, hs);
    gemm2_kernel<<<dim3(128, 8, NE), 256, 0, stream>>>(hq, hs, wd, sd, offs, dp0, dp1);
    combine_kernel<<<1024, 256, 0, stream>>>(dp0, dp1, ent, tkw, out);
}